// Round 2
// baseline (194.915 us; speedup 1.0000x reference)
//
#include <hip/hip_runtime.h>

typedef short bf16x8 __attribute__((ext_vector_type(8)));
typedef float f32x4  __attribute__((ext_vector_type(4)));

__device__ __forceinline__ unsigned short f32_to_bf16(float f) {
  union { float f; unsigned int u; } v; v.f = f;
  unsigned int u = v.u;
  u += 0x7fffu + ((u >> 16) & 1u);   // round-to-nearest-even
  return (unsigned short)(u >> 16);
}
__device__ __forceinline__ float bf16lo_to_f32(unsigned int u) {
  union { unsigned int u; float f; } v; v.u = u << 16; return v.f;
}
__device__ __forceinline__ float bf16hi_to_f32(unsigned int u) {
  union { unsigned int u; float f; } v; v.u = u & 0xffff0000u; return v.f;
}

// LDS row stride: 32 k-elements padded to 40 ushorts (80 B = 20 banks):
// consecutive fragment rows land 20 banks apart -> worst aliasing 2-way (free).
#define LDSTRIDE 40

// h = x @ W.T + b, h[0,:]=0, stored bf16.
// Block: 64 atoms x 256 cols; 4 waves, wave w owns cols [w*64, w*64+64).
// MFMA operands SWAPPED vs naive (A=W rows, B=x rows) so the D "row" field
// (quad*4+reg) indexes OUTPUT COLUMNS -> each lane holds 4 consecutive cols
// of one atom -> pack 4 bf16 -> single 8B store (16 stores/thread, not 64).
__global__ __launch_bounds__(256, 2) void gin_gemm(
    const float* __restrict__ x, const float* __restrict__ W,
    const float* __restrict__ bias, unsigned short* __restrict__ h, int M) {
  __shared__ __align__(16) unsigned short Xs[64 * LDSTRIDE];    // atoms  5 KB
  __shared__ __align__(16) unsigned short Ws[256 * LDSTRIDE];   // W rows 20 KB

  const int tid  = threadIdx.x;
  const int wid  = tid >> 6;
  const int lane = tid & 63;
  const int row0 = blockIdx.x * 64;

  f32x4 acc[4][4] = {};  // [ng (col group)][ag (atom group)]

  // staging mapping: thread covers 8 contiguous k's of one row
  const int srow = tid >> 2;          // 0..63
  const int sk0  = (tid & 3) << 3;    // 0,8,16,24
  int agrow = row0 + srow;
  if (agrow >= M) agrow = M - 1;      // clamp; stores guarded in epilogue
  const float* aRow = x + (size_t)agrow * 256 + sk0;
  const float* bRow = W + (size_t)srow * 256 + sk0;

  // per-thread bias: n = wid*64 + ng*16 + quad*4 + r
  const int quad = lane >> 4;
  const int c16  = lane & 15;
  float4 biasv[4];
#pragma unroll
  for (int ng = 0; ng < 4; ++ng)
    biasv[ng] = *(const float4*)(bias + wid * 64 + ng * 16 + quad * 4);

  for (int kt = 0; kt < 8; ++kt) {
    const int kb = kt * 32;
    {  // stage x: 64x32 f32 -> bf16
      float4 v0 = *(const float4*)(aRow + kb);
      float4 v1 = *(const float4*)(aRow + kb + 4);
      bf16x8 u;
      u[0] = (short)f32_to_bf16(v0.x); u[1] = (short)f32_to_bf16(v0.y);
      u[2] = (short)f32_to_bf16(v0.z); u[3] = (short)f32_to_bf16(v0.w);
      u[4] = (short)f32_to_bf16(v1.x); u[5] = (short)f32_to_bf16(v1.y);
      u[6] = (short)f32_to_bf16(v1.z); u[7] = (short)f32_to_bf16(v1.w);
      *(bf16x8*)(&Xs[srow * LDSTRIDE + sk0]) = u;
    }
#pragma unroll
    for (int j = 0; j < 4; ++j) {  // stage W: 256x32
      const float* p = bRow + (size_t)(j * 64) * 256 + kb;
      float4 v0 = *(const float4*)p;
      float4 v1 = *(const float4*)(p + 4);
      bf16x8 u;
      u[0] = (short)f32_to_bf16(v0.x); u[1] = (short)f32_to_bf16(v0.y);
      u[2] = (short)f32_to_bf16(v0.z); u[3] = (short)f32_to_bf16(v0.w);
      u[4] = (short)f32_to_bf16(v1.x); u[5] = (short)f32_to_bf16(v1.y);
      u[6] = (short)f32_to_bf16(v1.z); u[7] = (short)f32_to_bf16(v1.w);
      *(bf16x8*)(&Ws[(j * 64 + srow) * LDSTRIDE + sk0]) = u;
    }
    __syncthreads();

    const int r16 = lane & 15;
    const int qk  = (lane >> 4) << 3;  // k-offset 0/8/16/24
    bf16x8 wf[4], xf[4];
#pragma unroll
    for (int g = 0; g < 4; ++g)
      wf[g] = *(const bf16x8*)(&Ws[(wid * 64 + g * 16 + r16) * LDSTRIDE + qk]);
#pragma unroll
    for (int g = 0; g < 4; ++g)
      xf[g] = *(const bf16x8*)(&Xs[(g * 16 + r16) * LDSTRIDE + qk]);
#pragma unroll
    for (int ng = 0; ng < 4; ++ng)
#pragma unroll
      for (int ag = 0; ag < 4; ++ag)
        acc[ng][ag] = __builtin_amdgcn_mfma_f32_16x16x32_bf16(
            wf[ng], xf[ag], acc[ng][ag], 0, 0, 0);
    __syncthreads();
  }

  // epilogue: D row field = output col n = wid*64+ng*16+quad*4+r,
  //           D col field = atom = row0 + ag*16 + c16
#pragma unroll
  for (int ag = 0; ag < 4; ++ag) {
    const int atom = row0 + ag * 16 + c16;
    if (atom >= M) continue;
#pragma unroll
    for (int ng = 0; ng < 4; ++ng) {
      const int n0 = wid * 64 + ng * 16 + quad * 4;
      float v0 = acc[ng][ag][0] + biasv[ng].x;
      float v1 = acc[ng][ag][1] + biasv[ng].y;
      float v2 = acc[ng][ag][2] + biasv[ng].z;
      float v3 = acc[ng][ag][3] + biasv[ng].w;
      if (atom == 0) { v0 = v1 = v2 = v3 = 0.0f; }
      uint2 pk;
      pk.x = (unsigned int)f32_to_bf16(v0) | ((unsigned int)f32_to_bf16(v1) << 16);
      pk.y = (unsigned int)f32_to_bf16(v2) | ((unsigned int)f32_to_bf16(v3) << 16);
      *(uint2*)(h + (size_t)atom * 256 + n0) = pk;
    }
  }
}

// out[i] = relu(h[i] + sum_k h[b_from_a[a_from_b[i,k]]]); one wave per atom.
// Wave split in halves: each half-wave (32 lanes x 16B) covers a full 512B
// bf16 row per load -> 9 dwordx4 issues/atom instead of 17 dwordx2.
__global__ __launch_bounds__(256, 4) void gin_gather(
    const unsigned short* __restrict__ h, const int* __restrict__ b_from_a,
    const int* __restrict__ a_from_b, float* __restrict__ out, int N) {
  const int wid  = threadIdx.x >> 6;
  const int lane = threadIdx.x & 63;
  const int i = blockIdx.x * 4 + wid;
  if (i >= N) return;

  const int half = lane >> 5;      // 0: neighbors 0-7, 1: neighbors 8-15
  const int hl   = lane & 31;
  const int c0   = hl << 3;        // 8 cols per lane

  int src = 0;
  if (lane < 16) src = b_from_a[a_from_b[i * 16 + lane]];

  const unsigned short* hp = h + c0;

  // self row: both halves load (cached), only half 0 accumulates it
  float a0, a1, a2, a3, a4, a5, a6, a7;
  {
    uint4 v = *(const uint4*)(hp + (size_t)i * 256);
    const float selfw = half ? 0.0f : 1.0f;
    a0 = selfw * bf16lo_to_f32(v.x); a1 = selfw * bf16hi_to_f32(v.x);
    a2 = selfw * bf16lo_to_f32(v.y); a3 = selfw * bf16hi_to_f32(v.y);
    a4 = selfw * bf16lo_to_f32(v.z); a5 = selfw * bf16hi_to_f32(v.z);
    a6 = selfw * bf16lo_to_f32(v.w); a7 = selfw * bf16hi_to_f32(v.w);
  }
#pragma unroll
  for (int k = 0; k < 8; ++k) {
    int s = __shfl(src, half * 8 + k, 64);
    uint4 v = *(const uint4*)(hp + (size_t)s * 256);
    a0 += bf16lo_to_f32(v.x); a1 += bf16hi_to_f32(v.x);
    a2 += bf16lo_to_f32(v.y); a3 += bf16hi_to_f32(v.y);
    a4 += bf16lo_to_f32(v.z); a5 += bf16hi_to_f32(v.z);
    a6 += bf16lo_to_f32(v.w); a7 += bf16hi_to_f32(v.w);
  }
  // cross-half combine
  a0 += __shfl_xor(a0, 32, 64); a1 += __shfl_xor(a1, 32, 64);
  a2 += __shfl_xor(a2, 32, 64); a3 += __shfl_xor(a3, 32, 64);
  a4 += __shfl_xor(a4, 32, 64); a5 += __shfl_xor(a5, 32, 64);
  a6 += __shfl_xor(a6, 32, 64); a7 += __shfl_xor(a7, 32, 64);

  // lane stores 16B: half 0 -> cols [c0,c0+4), half 1 -> cols [c0+4,c0+8)
  float4 r;
  if (half == 0) {
    r.x = fmaxf(a0, 0.0f); r.y = fmaxf(a1, 0.0f);
    r.z = fmaxf(a2, 0.0f); r.w = fmaxf(a3, 0.0f);
  } else {
    r.x = fmaxf(a4, 0.0f); r.y = fmaxf(a5, 0.0f);
    r.z = fmaxf(a6, 0.0f); r.w = fmaxf(a7, 0.0f);
  }
  *(float4*)(out + (size_t)i * 256 + c0 + half * 4) = r;
}

extern "C" void kernel_launch(void* const* d_in, const int* in_sizes, int n_in,
                              void* d_out, int out_size, void* d_ws, size_t ws_size,
                              hipStream_t stream) {
  const float* x        = (const float*)d_in[0];
  const float* W        = (const float*)d_in[1];
  const float* b        = (const float*)d_in[2];
  const int*   b_from_a = (const int*)d_in[3];
  const int*   a_from_b = (const int*)d_in[4];
  float*       out      = (float*)d_out;
  const int M = in_sizes[0] / 256;  // 50000 atoms

  unsigned short* h = (unsigned short*)d_ws;  // bf16 h, 25.6 MB

  gin_gemm<<<(M + 63) / 64, 256, 0, stream>>>(x, W, b, h, M);
  gin_gather<<<(M + 3) / 4, 256, 0, stream>>>(h, b_from_a, a_from_b, out, M);
}